// Round 3
// baseline (2730.218 us; speedup 1.0000x reference)
//
#include <hip/hip_runtime.h>

#define N_NODES     8192
#define N_FEAT      1024
#define N_FILT      4
#define MAXDEG      8

// ---------------------------------------------------------------------------
// Kernel A: filt = relu(X @ W1^T + b1) @ W2^T + b2     -> (N_NODES, 4)
// ---------------------------------------------------------------------------
__global__ __launch_bounds__(256) void filt_kernel(
    const float* __restrict__ X, const float* __restrict__ W1,
    const float* __restrict__ b1, const float* __restrict__ W2,
    const float* __restrict__ b2, float* __restrict__ filt)
{
    const int node = blockIdx.x * 8 + (threadIdx.x >> 5);
    const int h    = threadIdx.x & 31;
    const float* xr = X  + (size_t)node * N_FEAT;
    const float* wr = W1 + (size_t)h    * N_FEAT;
    float acc = 0.f;
    for (int j = 0; j < N_FEAT; j += 4) {
        float4 xv = *reinterpret_cast<const float4*>(xr + j);
        float4 wv = *reinterpret_cast<const float4*>(wr + j);
        acc += xv.x * wv.x + xv.y * wv.y + xv.z * wv.z + xv.w * wv.w;
    }
    float hv = fmaxf(acc + b1[h], 0.f);
    #pragma unroll
    for (int fo = 0; fo < N_FILT; ++fo) {
        float v = hv * W2[fo * 32 + h];
        for (int off = 16; off; off >>= 1) v += __shfl_xor(v, off, 32);
        if (h == 0) filt[node * N_FILT + fo] = v + b2[fo];
    }
}

// ---------------------------------------------------------------------------
// Kernel W: wsum[j] = sum_h Wt[h][j] (j=0..7), wsum[8] = sum_h bt[h]
// ---------------------------------------------------------------------------
__global__ void wsum_kernel(const float* __restrict__ Wt,
                            const float* __restrict__ bt,
                            float* __restrict__ wsum)
{
    int t = threadIdx.x;
    if (t < 8) {
        float s = 0.f;
        for (int hh = 0; hh < 64; ++hh) s += Wt[hh * 8 + t];
        wsum[t] = s;
    } else if (t == 8) {
        float s = 0.f;
        for (int hh = 0; hh < 64; ++hh) s += bt[hh];
        wsum[8] = s;
    }
}

// ---------------------------------------------------------------------------
// Kernel B: per-filtration 0-dim persistence, pos-space union-find,
// 8-steps-per-wave-group batching.
//
// Lane layout in the serial wave: row = lane>>3 (handles step s+row),
// slot = lane&7 (edge index). x = et[s*8+lane] (et = min(pos[nbr],step),
// so invalid/self edges degenerate to the vertex itself). The vertex root
// of step s+r is provably s+r (virgin) and is folded in via min(t, s+row).
//
// Group algorithm:
//   1. lockstep find for all 64 lanes against pre-group parent state
//   2. 8 resolution rounds r=0..7:
//        m = DPP-min over 8-lane row  (3 ops, all rows at once), min w/ s+row
//        row r: compress par[x]=m; kill p!=m (death=s+r); vertex kill
//        rounds r<7: 3-ballot test decides if later rows must refresh
//        (single ds_read p=par[p] restores true roots; provably sufficient)
// Invariant: roots are only modified by kill writes; background compressor
// waves only move pointers along real ancestor chains (monotone, root-safe).
// ---------------------------------------------------------------------------
__device__ __forceinline__ int row8_min(int v) {
    int t = min(v, __builtin_amdgcn_mov_dpp(v, 0xB1, 0xF, 0xF, true));   // quad xor1
    t = min(t, __builtin_amdgcn_mov_dpp(t, 0x4E, 0xF, 0xF, true));       // quad xor2
    t = min(t, __builtin_amdgcn_mov_dpp(t, 0x141, 0xF, 0xF, true));      // row half mirror
    return t;
}

__global__ __launch_bounds__(256) void persist_kernel(
    const float* __restrict__ filt,       // [N_NODES][4]
    const int*   __restrict__ edge_dst,   // [N_NODES*8]
    unsigned short* __restrict__ ews,     // [N_FILT][N_NODES*8] step-edge table
    unsigned short* __restrict__ posd16)  // [N_FILT][2][N_NODES] (pos, death)
{
    const int f   = blockIdx.x;
    const int tid = threadIdx.x;

    __shared__ __align__(16) unsigned char smem[65536];
    float*          s_val = reinterpret_cast<float*>(smem);
    volatile unsigned short* s_par =
        reinterpret_cast<volatile unsigned short*>(smem);          // 16 KB (aliases s_val)
    unsigned short* s_dth = reinterpret_cast<unsigned short*>(smem + 16384);
    unsigned short* s_idx = reinterpret_cast<unsigned short*>(smem + 32768);
    unsigned short* s_pos = reinterpret_cast<unsigned short*>(smem + 49152);
    volatile int*   s_done = reinterpret_cast<volatile int*>(smem + 32768); // aliases s_idx[0:2]

    // ---- phase 1: load + bitonic sort (value, idx) ----
    for (int v = tid; v < N_NODES; v += 256) {
        s_val[v] = filt[v * N_FILT + f];
        s_idx[v] = (unsigned short)v;
    }
    __syncthreads();
    for (int k = 2; k <= N_NODES; k <<= 1) {
        for (int j = k >> 1; j > 0; j >>= 1) {
            for (int t = tid; t < N_NODES / 2; t += 256) {
                int i = ((t & ~(j - 1)) << 1) | (t & (j - 1));
                int p = i | j;
                bool up = ((i & k) == 0);
                float va = s_val[i], vb = s_val[p];
                unsigned short ia = s_idx[i], ib = s_idx[p];
                bool agtb = (va > vb) || (va == vb && ia > ib);
                if (agtb == up) {
                    s_val[i] = vb; s_val[p] = va;
                    s_idx[i] = ib; s_idx[p] = ia;
                }
            }
            __syncthreads();
        }
    }

    // ---- phase 2: pos ----
    for (int v = tid; v < N_NODES; v += 256)
        s_pos[s_idx[v]] = (unsigned short)v;
    __syncthreads();

    // ---- phase 3: static edge filter into global ws + init parent/death ----
    unsigned short* et = ews + (size_t)f * (N_NODES * MAXDEG);
    for (int e = tid; e < N_NODES * MAXDEG; e += 256) {
        int s = e >> 3, k = e & 7;
        int v = (int)s_idx[s];
        int u = edge_dst[v * MAXDEG + k];
        int q = (int)s_pos[u];
        et[e] = (unsigned short)(q < s ? q : s);   // invalid/self -> s
    }
    for (int v = tid; v < N_NODES; v += 256) {
        reinterpret_cast<unsigned short*>(smem)[v] = (unsigned short)v; // parent
        s_dth[v] = 0;
    }
    __syncthreads();
    if (tid == 0) *s_done = 0;
    __syncthreads();

    // ---- phase 4: grouped serial union-find (wave 0) + background compress ----
    if (tid < 64) {
        const int lane = tid;
        const int row  = lane >> 3;
        const int slot = lane & 7;
        const unsigned short* etl = et + lane;
        int b0 = (int)etl[0];
        int b1 = (int)etl[64];
        for (int s = 0; s < N_NODES; s += 8) {
            const int x = b0;
            b0 = b1;
            int pf = s * 8 + 128;
            if (pf > (N_NODES - 8) * 8) pf = (N_NODES - 8) * 8;
            b1 = (int)etl[pf];

            // lockstep find against pre-group state
            int p = x;
            for (;;) {
                int q = (int)s_par[p];
                if (__all(q == p)) break;
                p = q;
            }

            // 8 resolution rounds
            #pragma unroll
            for (int r = 0; r < 8; ++r) {
                const int sv = s + r;
                int m = min(row8_min(p), s + row);   // row-local elder (incl. vertex)
                const bool isrow = (row == r);
                if (isrow) {
                    s_par[x] = (unsigned short)m;                     // source compress
                    if (p != m) {                                     // kill root p
                        s_par[p] = (unsigned short)m;
                        s_dth[p] = (unsigned short)sv;
                    }
                    if (slot == 0 && m != sv) {                       // vertex merge
                        s_par[sv] = (unsigned short)m;
                        s_dth[sv] = (unsigned short)sv;
                    }
                }
                if (r < 7) {
                    unsigned long long bk = __ballot(isrow && (p != m) && (p != sv));
                    unsigned long long bv = __ballot((row > r) && (p == sv));
                    unsigned long long bd = __ballot(isrow && (m != sv));
                    if (bk != 0ull || (bv != 0ull && bd != 0ull)) {
                        if (row > r) p = (int)s_par[p];               // single-read refresh
                    }
                }
            }
        }
        if (lane == 0) *s_done = 1;
    } else {
        // monotone lock-free pointer halving; 'g != p' guard keeps roots intact.
        while (!(*s_done)) {
            for (int v = tid - 64; v < N_NODES; v += 192) {
                int p = (int)s_par[v];
                int g = (int)s_par[p];
                if (g != p) s_par[v] = (unsigned short)g;
            }
            __builtin_amdgcn_s_sleep(2);
        }
    }
    __syncthreads();

    // ---- phase 5: emit (pos, death) as u16; death 0 -> N ----
    unsigned short* pd = posd16 + (size_t)f * (2 * N_NODES);
    for (int n = tid; n < N_NODES; n += 256) {
        int p = (int)s_pos[n];
        int d = (int)s_dth[p];
        pd[n]            = (unsigned short)p;
        pd[N_NODES + n]  = (unsigned short)(d ? d : N_NODES);
    }
}

// ---------------------------------------------------------------------------
// Kernel P: pooled[n] = wsum[8] + sum_f pos_f[n]*wsum[2f] + death_f[n]*wsum[2f+1]
// ---------------------------------------------------------------------------
__global__ __launch_bounds__(256) void pooled_kernel(
    const unsigned short* __restrict__ posd16, const float* __restrict__ wsum,
    float* __restrict__ pooled)
{
    int n = blockIdx.x * 256 + threadIdx.x;
    float acc = wsum[8];
    #pragma unroll
    for (int i = 0; i < N_FILT; ++i) {
        acc += (float)posd16[i * 2 * N_NODES + n]           * wsum[2 * i + 0]
             + (float)posd16[i * 2 * N_NODES + N_NODES + n] * wsum[2 * i + 1];
    }
    pooled[n] = acc;
}

// ---------------------------------------------------------------------------
// Kernel C: out[n][f] = X[n][f] + pooled[n]*Wr[f] + br[f]
// ---------------------------------------------------------------------------
__global__ __launch_bounds__(256) void out_kernel(
    const float* __restrict__ X, const float* __restrict__ Wr,
    const float* __restrict__ br, const float* __restrict__ pooled,
    float* __restrict__ out)
{
    const int node = blockIdx.x;
    const float pl = pooled[node];
    const int fb = threadIdx.x * 4;
    const float4 xv = *reinterpret_cast<const float4*>(X + (size_t)node * N_FEAT + fb);
    const float4 wv = *reinterpret_cast<const float4*>(Wr + fb);
    const float4 bv = *reinterpret_cast<const float4*>(br + fb);
    float4 o;
    o.x = xv.x + pl * wv.x + bv.x;
    o.y = xv.y + pl * wv.y + bv.y;
    o.z = xv.z + pl * wv.z + bv.z;
    o.w = xv.w + pl * wv.w + bv.w;
    *reinterpret_cast<float4*>(out + (size_t)node * N_FEAT + fb) = o;
}

// ---------------------------------------------------------------------------
extern "C" void kernel_launch(void* const* d_in, const int* in_sizes, int n_in,
                              void* d_out, int out_size, void* d_ws, size_t ws_size,
                              hipStream_t stream) {
    const float* X  = (const float*)d_in[0];
    const int* edge = (const int*)d_in[1];
    const float* W1 = (const float*)d_in[2];
    const float* b1 = (const float*)d_in[3];
    const float* W2 = (const float*)d_in[4];
    const float* b2 = (const float*)d_in[5];
    const float* Wt = (const float*)d_in[6];
    const float* bt = (const float*)d_in[7];
    const float* Wr = (const float*)d_in[8];
    const float* br = (const float*)d_in[9];

    const int* edge_dst = edge + N_NODES * MAXDEG;  // row 1 of edge_list

    // ws layout (bytes):
    //   [0,        131072)  filt   f32[8192*4]
    //   [131072,   655360)  ews    u16[4][65536]
    //   [655360,   786432)  posd16 u16[4][2][8192]
    //   [786432,   786496)  wsum   f32[16]
    //   [786496,   819264)  pooled f32[8192]
    char* wsb = (char*)d_ws;
    float*          filt   = (float*)(wsb);
    unsigned short* ews    = (unsigned short*)(wsb + 131072);
    unsigned short* posd16 = (unsigned short*)(wsb + 655360);
    float*          wsum   = (float*)(wsb + 786432);
    float*          pooled = (float*)(wsb + 786496);

    hipLaunchKernelGGL(filt_kernel,  dim3(N_NODES / 8), dim3(256), 0, stream,
                       X, W1, b1, W2, b2, filt);
    hipLaunchKernelGGL(wsum_kernel,  dim3(1), dim3(64), 0, stream, Wt, bt, wsum);
    hipLaunchKernelGGL(persist_kernel, dim3(N_FILT), dim3(256), 0, stream,
                       filt, edge_dst, ews, posd16);
    hipLaunchKernelGGL(pooled_kernel, dim3(N_NODES / 256), dim3(256), 0, stream,
                       posd16, wsum, pooled);
    hipLaunchKernelGGL(out_kernel,   dim3(N_NODES), dim3(256), 0, stream,
                       X, Wr, br, pooled, (float*)d_out);
}